// Round 5
// baseline (101.165 us; speedup 1.0000x reference)
//
#include <hip/hip_runtime.h>
#include <hip/hip_bf16.h>

// Problem constants
#define NTOK 2048
#define TOPK 2
#define HS   512
#define FFN  2048
#define NE   8
#define TASSIGN (NTOK*TOPK)   // 4096
#define PAD  5120             // 4096 + 8*128
#define MAXT128 40
#define MAXT64  72

typedef __attribute__((ext_vector_type(8))) short bf16x8;
typedef __attribute__((ext_vector_type(4))) float f32x4;

// ws layout (byte offsets); total ~77.7 MB
static const size_t OFF_XBF  = 0;            // [NTOK*HS] bf16
static const size_t OFF_W1T  = 2097152;      // [E][FFN][HS] bf16
static const size_t OFF_W2T  = 18874368;     // [E][HS][FFN] bf16
static const size_t OFF_H    = 35651584;     // [PAD][FFN] bf16
static const size_t OFF_OUTV = 56623104;     // [2][PAD][HS] f32 (split-K partials)
static const size_t OFF_RT   = 77594624;     // rowtok [PAD] int
static const size_t OFF_HROF = 77615104;     // hrof [TASSIGN] int
static const size_t OFF_TE128= 77631488;
static const size_t OFF_TR128= 77631648;
static const size_t OFF_TE64 = 77631808;
static const size_t OFF_TR64 = 77632096;

__device__ __forceinline__ unsigned short f2bf(float f) {
    union { __hip_bfloat16 h; unsigned short u; } v;
    v.h = __float2bfloat16(f);
    return v.u;
}

__device__ __forceinline__ int swz(int r, int byte_off) {
    return byte_off ^ ((r & 7) << 4);
}

#define GLOAD16(gsrc, ldst) \
    __builtin_amdgcn_global_load_lds((const __attribute__((address_space(1))) void*)(gsrc), \
                                     (__attribute__((address_space(3))) void*)(ldst), 16, 0, 0)

// ---- fused prep: setup (block 0) + x->bf16 (1024) + w1 transpose (8192) + w2 transpose (8192) ----
__device__ __forceinline__ void dev_transpose(const float* __restrict__ in,
                                              unsigned short* __restrict__ out,
                                              int R, int C, int e, int rb, int cb, int tid) {
    __shared__ unsigned short t[32][33];
    int tx = tid & 31, ty = tid >> 5;          // 32 x 8
    const float* ip = in + (size_t)e * R * C;
    unsigned short* op = out + (size_t)e * C * R;
#pragma unroll
    for (int i = 0; i < 4; i++) {
        int r = ty + i * 8;
        t[r][tx] = f2bf(ip[(size_t)(rb + r) * C + cb + tx]);
    }
    __syncthreads();
#pragma unroll
    for (int i = 0; i < 4; i++) {
        int c = ty + i * 8;
        op[(size_t)(cb + c) * R + rb + tx] = t[tx][c];
    }
}

__global__ __launch_bounds__(256) void k_prep(
        const float* __restrict__ x, const float* __restrict__ w1,
        const float* __restrict__ w2, const int* __restrict__ ei,
        unsigned short* __restrict__ xbf, unsigned short* __restrict__ w1T,
        unsigned short* __restrict__ w2T,
        int* __restrict__ rowtok, int* __restrict__ hrof,
        int* __restrict__ te128, int* __restrict__ tr128,
        int* __restrict__ te64, int* __restrict__ tr64) {
    int b = blockIdx.x;
    int tid = threadIdx.x;
    if (b == 0) {
        // setup: counting sort by expert, 128-padded segments, two tile tables
        __shared__ int cnt[NE], offpad[NE], cur[NE];
        for (int i = tid; i < PAD; i += 256) rowtok[i] = 0;   // pad rows -> token 0 (harmless)
        if (tid < NE) cnt[tid] = 0;
        __syncthreads();
        for (int a = tid; a < TASSIGN; a += 256) atomicAdd(&cnt[ei[a]], 1);
        __syncthreads();
        if (tid == 0) {
            int o = 0, t1 = 0, t2 = 0;
            for (int e = 0; e < NE; e++) {
                offpad[e] = o; cur[e] = 0;
                for (int r = 0; r < cnt[e]; r += 128) { te128[t1] = e; tr128[t1] = o + r; t1++; }
                for (int r = 0; r < cnt[e]; r += 64)  { te64[t2]  = e; tr64[t2]  = o + r; t2++; }
                o += (cnt[e] + 127) / 128 * 128;
            }
            for (; t1 < MAXT128; t1++) te128[t1] = -1;
            for (; t2 < MAXT64;  t2++) te64[t2]  = -1;
        }
        __syncthreads();
        for (int a = tid; a < TASSIGN; a += 256) {
            int e = ei[a];
            int r = atomicAdd(&cur[e], 1);
            int hr = offpad[e] + r;
            rowtok[hr] = a >> 1;       // token = assignment / TOPK
            hrof[a] = hr;
        }
    } else if (b < 1 + 1024) {
        int i = ((b - 1) * 256 + tid) * 4;
        float4 v = *(const float4*)(x + i);
        ushort4 o;
        o.x = f2bf(v.x); o.y = f2bf(v.y); o.z = f2bf(v.z); o.w = f2bf(v.w);
        *(ushort4*)(xbf + i) = o;
    } else if (b < 1 + 1024 + 8192) {
        // w1 [E][HS][FFN] -> w1T [E][FFN][HS]: R=HS, C=FFN
        int blk = b - 1025;
        int e = blk >> 10, rem = blk & 1023;
        dev_transpose(w1, w1T, HS, FFN, e, (rem >> 6) * 32, (rem & 63) * 32, tid);
    } else {
        // w2 [E][FFN][HS] -> w2T [E][HS][FFN]: R=FFN, C=HS
        int blk = b - 9217;
        int e = blk >> 10, rem = blk & 1023;
        dev_transpose(w2, w2T, FFN, HS, e, (rem >> 4) * 32, (rem & 15) * 32, tid);
    }
}

// ---- grouped GEMM: 2-phase double-buffered global_load_lds pipeline ----
// G1=true:  out = gelu(A_gathered @ B^T-layout), bf16 out
// G1=false: out = A @ B^T-layout, f32 out; blockIdx.z selects K-slice (split-K),
//           each slice writes its own [PAD][HS] partial buffer.
template<int BM, int BN, int KFULL, int KLOC, bool G1>
__global__ __launch_bounds__(256) void k_gemm(
        const unsigned short* __restrict__ A,
        const unsigned short* __restrict__ B,
        void* __restrict__ outp,
        const int* __restrict__ rowtok,
        const int* __restrict__ te, const int* __restrict__ tr, int N) {
    constexpr int MI = BM / 32, NJ = BN / 32;
    constexpr int PA = BM / 32, PB = BN / 32;       // gload sets of 256 lanes x 16B
    constexpr int ABYTES = BM * 64 * 2, BBYTES = BN * 64 * 2;
    constexpr int NSTEP = KLOC / 64;
    static_assert(NSTEP % 2 == 0, "even steps");

    int mt = blockIdx.y;
    int e = te[mt];
    if (e < 0) return;
    int hr0 = tr[mt];
    int ct = blockIdx.x;
    int kz = blockIdx.z;
    int k0 = kz * KLOC;

    __shared__ int4 ldsv[(2 * (ABYTES + BBYTES)) / 16];
    char* A0 = (char*)ldsv;
    char* A1 = A0 + ABYTES;
    char* B0 = A1 + ABYTES;
    char* B1 = B0 + BBYTES;

    int tid = threadIdx.x;
    int lane = tid & 63, wave = tid >> 6;
    int wm = wave >> 1, wn = wave & 1;

    // per-thread pre-swizzled global sources (chunk c8 of row r fetched from c8^(r&7))
    const char* asrc[PA];
    const char* bsrc[PB];
    int adoff[PA], bdoff[PB];
#pragma unroll
    for (int p = 0; p < PA; p++) {
        int idx = p * 256 + tid;
        int r = idx >> 3, c8 = idx & 7;
        int c8s = c8 ^ (r & 7);
        size_t row = G1 ? (size_t)rowtok[hr0 + r] : (size_t)(hr0 + r);
        asrc[p] = (const char*)(A + row * KFULL + k0) + c8s * 16;
        adoff[p] = (p * 256 + wave * 64) * 16;      // wave-uniform linear LDS dest
    }
#pragma unroll
    for (int p = 0; p < PB; p++) {
        int idx = p * 256 + tid;
        int r = idx >> 3, c8 = idx & 7;
        int c8s = c8 ^ (r & 7);
        bsrc[p] = (const char*)(B + ((size_t)e * N + (size_t)ct * BN + r) * KFULL + k0) + c8s * 16;
        bdoff[p] = (p * 256 + wave * 64) * 16;
    }

    f32x4 acc[MI][NJ] = {};

    auto stage = [&](char* Ad, char* Bd, int s) {
        int kb = s * 128;                            // 64 k-elems * 2B
#pragma unroll
        for (int p = 0; p < PA; p++) GLOAD16(asrc[p] + kb, Ad + adoff[p]);
#pragma unroll
        for (int p = 0; p < PB; p++) GLOAD16(bsrc[p] + kb, Bd + bdoff[p]);
    };
    auto compute = [&](const char* As, const char* Bs) {
#pragma unroll
        for (int kk = 0; kk < 64; kk += 32) {
            bf16x8 af[MI], bfv[NJ];
#pragma unroll
            for (int i = 0; i < MI; i++) {
                int ar = wm * (BM / 2) + i * 16 + (lane & 15);
                af[i] = *(const bf16x8*)(As + swz(ar, ar * 128 + kk * 2 + (lane >> 4) * 16));
            }
#pragma unroll
            for (int j = 0; j < NJ; j++) {
                int bc = wn * (BN / 2) + j * 16 + (lane & 15);
                bfv[j] = *(const bf16x8*)(Bs + swz(bc, bc * 128 + kk * 2 + (lane >> 4) * 16));
            }
#pragma unroll
            for (int i = 0; i < MI; i++)
#pragma unroll
                for (int j = 0; j < NJ; j++)
                    acc[i][j] = __builtin_amdgcn_mfma_f32_16x16x32_bf16(af[i], bfv[j], acc[i][j], 0, 0, 0);
        }
    };

    // prologue
    stage(A0, B0, 0);
    __syncthreads();                                 // buf0 ready
    // 2-phase pipeline: issue next-step loads before computing current step;
    // the single __syncthreads per step drains them only AFTER compute.
#pragma unroll 1
    for (int s = 0; s < NSTEP; s += 2) {
        if (s + 1 < NSTEP) stage(A1, B1, s + 1);
        compute(A0, B0);
        __syncthreads();
        if (s + 2 < NSTEP) stage(A0, B0, s + 2);
        compute(A1, B1);
        __syncthreads();
    }

    if constexpr (G1) {
        unsigned short* O = (unsigned short*)outp;
#pragma unroll
        for (int i = 0; i < MI; i++)
#pragma unroll
            for (int j = 0; j < NJ; j++)
#pragma unroll
                for (int q = 0; q < 4; q++) {
                    int row = hr0 + wm * (BM / 2) + i * 16 + (lane >> 4) * 4 + q;
                    int col = ct * BN + wn * (BN / 2) + j * 16 + (lane & 15);
                    float v = acc[i][j][q];
                    float g = 0.5f * v * (1.0f + erff(v * 0.70710678118f));
                    O[(size_t)row * N + col] = f2bf(g);
                }
    } else {
        float* O = (float*)outp + (size_t)kz * PAD * HS;
#pragma unroll
        for (int i = 0; i < MI; i++)
#pragma unroll
            for (int j = 0; j < NJ; j++)
#pragma unroll
                for (int q = 0; q < 4; q++) {
                    int row = hr0 + wm * (BM / 2) + i * 16 + (lane >> 4) * 4 + q;
                    int col = ct * BN + wn * (BN / 2) + j * 16 + (lane & 15);
                    O[(size_t)row * N + col] = acc[i][j][q];
                }
    }
}

// ---- combine (float4): sum split-K partials; y[t] = w0*o0 + w1*o1 ;
//      buffer[t][0..7] fully written (zeros incl.) -> no memset anywhere ----
__global__ __launch_bounds__(256) void k_combine(
        const float4* __restrict__ outv, const int* __restrict__ ei,
        const float* __restrict__ ew, const int* __restrict__ hrof,
        float4* __restrict__ y, float4* __restrict__ buf) {
    constexpr int SPLIT_OFF = PAD * HS / 4;   // float4 stride between partials
    int g = blockIdx.x * 256 + threadIdx.x;   // over NTOK*HS/4
    int t = g >> 7, c4 = g & 127;             // HS/4 = 128
    int a0 = 2 * t, a1 = a0 + 1;
    int h0 = hrof[a0], h1 = hrof[a1];
    float4 p0a = outv[(size_t)h0 * (HS / 4) + c4];
    float4 p0b = outv[SPLIT_OFF + (size_t)h0 * (HS / 4) + c4];
    float4 p1a = outv[(size_t)h1 * (HS / 4) + c4];
    float4 p1b = outv[SPLIT_OFF + (size_t)h1 * (HS / 4) + c4];
    float4 o0 = make_float4(p0a.x + p0b.x, p0a.y + p0b.y, p0a.z + p0b.z, p0a.w + p0b.w);
    float4 o1 = make_float4(p1a.x + p1b.x, p1a.y + p1b.y, p1a.z + p1b.z, p1a.w + p1b.w);
    float w0 = ew[a0], w1 = ew[a1];
    y[g] = make_float4(w0 * o0.x + w1 * o1.x, w0 * o0.y + w1 * o1.y,
                       w0 * o0.z + w1 * o1.z, w0 * o0.w + w1 * o1.w);
    int e0 = ei[a0], e1 = ei[a1];
    size_t base = (size_t)t * (NE * HS / 4) + c4;
#pragma unroll
    for (int e = 0; e < NE; e++) {
        float4 v = make_float4(0.f, 0.f, 0.f, 0.f);
        if (e == e0) { v.x += o0.x; v.y += o0.y; v.z += o0.z; v.w += o0.w; }
        if (e == e1) { v.x += o1.x; v.y += o1.y; v.z += o1.z; v.w += o1.w; }
        buf[base + (size_t)e * (HS / 4)] = v;
    }
}

extern "C" void kernel_launch(void* const* d_in, const int* in_sizes, int n_in,
                              void* d_out, int out_size, void* d_ws, size_t ws_size,
                              hipStream_t stream) {
    const float* x  = (const float*)d_in[0];
    const float* ew = (const float*)d_in[1];
    const int*   ei = (const int*)d_in[2];
    const float* w1 = (const float*)d_in[3];
    const float* w2 = (const float*)d_in[4];

    char* ws = (char*)d_ws;
    unsigned short* xbf  = (unsigned short*)(ws + OFF_XBF);
    unsigned short* w1T  = (unsigned short*)(ws + OFF_W1T);
    unsigned short* w2T  = (unsigned short*)(ws + OFF_W2T);
    unsigned short* Hb   = (unsigned short*)(ws + OFF_H);
    float*          outv = (float*)(ws + OFF_OUTV);
    int*            rowtok = (int*)(ws + OFF_RT);
    int*            hrof   = (int*)(ws + OFF_HROF);
    int*            te128  = (int*)(ws + OFF_TE128);
    int*            tr128  = (int*)(ws + OFF_TR128);
    int*            te64   = (int*)(ws + OFF_TE64);
    int*            tr64   = (int*)(ws + OFF_TR64);

    float* y   = (float*)d_out;
    float* buf = (float*)d_out + (size_t)NTOK * HS;

    // fused prep: setup + xcvt + both weight transposes (independent work, one launch)
    k_prep<<<1 + 1024 + 8192 + 8192, 256, 0, stream>>>(
        x, w1, w2, ei, xbf, w1T, w2T, rowtok, hrof, te128, tr128, te64, tr64);
    // GEMM1 + gelu -> H (bf16): 128x128 tiles, grid 16 x 40 = 640 blocks
    k_gemm<128, 128, HS, HS, true><<<dim3(FFN / 128, MAXT128), 256, 0, stream>>>(
        xbf, w1T, Hb, rowtok, te128, tr128, FFN);
    // GEMM2 -> outv partials (f32): 64x64 tiles, split-K=2, grid 8 x 72 x 2 = 1152 blocks
    k_gemm<64, 64, FFN, FFN / 2, false><<<dim3(HS / 64, MAXT64, 2), 256, 0, stream>>>(
        Hb, w2T, outv, rowtok, te64, tr64, HS);
    // combine split-K partials into y and buffer (writes ALL buffer slots)
    k_combine<<<NTOK * HS / 4 / 256, 256, 0, stream>>>(
        (const float4*)outv, ei, ew, hrof, (float4*)y, (float4*)buf);
}

// Round 6
// 95.005 us; speedup vs baseline: 1.0648x; 1.0648x over previous
//
#include <hip/hip_runtime.h>
#include <hip/hip_bf16.h>

// Problem constants
#define NTOK 2048
#define TOPK 2
#define HS   512
#define FFN  2048
#define NE   8
#define TASSIGN (NTOK*TOPK)   // 4096
#define PAD  5120             // 4096 + 8*128
#define MAXT128 40
#define MAXT64  72

typedef __attribute__((ext_vector_type(8))) short bf16x8;
typedef __attribute__((ext_vector_type(4))) float f32x4;

// ws layout (byte offsets); total ~77.7 MB
static const size_t OFF_XBF  = 0;            // [NTOK*HS] bf16
static const size_t OFF_W1T  = 2097152;      // [E][FFN][HS] bf16
static const size_t OFF_W2T  = 18874368;     // [E][HS][FFN] bf16
static const size_t OFF_H    = 35651584;     // [PAD][FFN] bf16
static const size_t OFF_OUTV = 56623104;     // [2][PAD][HS] f32 (split-K partials)
static const size_t OFF_RT   = 77594624;     // rowtok [PAD] int
static const size_t OFF_HROF = 77615104;     // hrof [TASSIGN] int
static const size_t OFF_TE128= 77631488;
static const size_t OFF_TR128= 77631648;
static const size_t OFF_TE64 = 77631808;
static const size_t OFF_TR64 = 77632096;

__device__ __forceinline__ unsigned short f2bf(float f) {
    union { __hip_bfloat16 h; unsigned short u; } v;
    v.h = __float2bfloat16(f);
    return v.u;
}

__device__ __forceinline__ int swz(int r, int byte_off) {
    return byte_off ^ ((r & 7) << 4);
}

#define GLOAD16(gsrc, ldst) \
    __builtin_amdgcn_global_load_lds((const __attribute__((address_space(1))) void*)(gsrc), \
                                     (__attribute__((address_space(3))) void*)(ldst), 16, 0, 0)

// ---- strip transpose: in [E][R][C] f32 -> out [E][C][R] bf16, one 32-row strip,
//      ncb 32-col tiles starting at cb0 (LDS buffer passed in, 32*33 ushorts) ----
__device__ __forceinline__ void tr_strip(const float* __restrict__ in,
                                         unsigned short* __restrict__ out,
                                         int R, int C, int e, int rb, int cb0, int ncb,
                                         int tid, unsigned short* t) {
    int tx = tid & 31, ty = tid >> 5;          // 32 x 8
    const float* ip = in + (size_t)e * R * C;
    unsigned short* op = out + (size_t)e * C * R;
#pragma unroll 1
    for (int it = 0; it < ncb; ++it) {
        int cb = (cb0 + it) * 32;
        __syncthreads();
#pragma unroll
        for (int i = 0; i < 4; i++) {
            int r = ty + i * 8;
            t[r * 33 + tx] = f2bf(ip[(size_t)(rb + r) * C + cb + tx]);
        }
        __syncthreads();
#pragma unroll
        for (int i = 0; i < 4; i++) {
            int c = ty + i * 8;
            op[(size_t)(cb + c) * R + rb + tx] = t[tx * 33 + c];
        }
    }
}

// ---- prep1: setup (block 0) + x->bf16 (1024) + w1 strip-transpose (512) ----
__global__ __launch_bounds__(256) void k_prep1(
        const float* __restrict__ x, const float* __restrict__ w1,
        const int* __restrict__ ei,
        unsigned short* __restrict__ xbf, unsigned short* __restrict__ w1T,
        int* __restrict__ rowtok, int* __restrict__ hrof,
        int* __restrict__ te128, int* __restrict__ tr128,
        int* __restrict__ te64, int* __restrict__ tr64) {
    __shared__ unsigned short tsh[32 * 33];
    int b = blockIdx.x;
    int tid = threadIdx.x;
    if (b == 0) {
        // setup: counting sort by expert, 128-padded segments, two tile tables
        __shared__ int cnt[NE], offpad[NE], cur[NE];
        for (int i = tid; i < PAD; i += 256) rowtok[i] = 0;   // pad rows -> token 0 (harmless)
        if (tid < NE) cnt[tid] = 0;
        __syncthreads();
        for (int a = tid; a < TASSIGN; a += 256) atomicAdd(&cnt[ei[a]], 1);
        __syncthreads();
        if (tid == 0) {
            int o = 0, t1 = 0, t2 = 0;
            for (int e = 0; e < NE; e++) {
                offpad[e] = o; cur[e] = 0;
                for (int r = 0; r < cnt[e]; r += 128) { te128[t1] = e; tr128[t1] = o + r; t1++; }
                for (int r = 0; r < cnt[e]; r += 64)  { te64[t2]  = e; tr64[t2]  = o + r; t2++; }
                o += (cnt[e] + 127) / 128 * 128;
            }
            for (; t1 < MAXT128; t1++) te128[t1] = -1;
            for (; t2 < MAXT64;  t2++) te64[t2]  = -1;
        }
        __syncthreads();
        for (int a = tid; a < TASSIGN; a += 256) {
            int e = ei[a];
            int r = atomicAdd(&cur[e], 1);
            int hr = offpad[e] + r;
            rowtok[hr] = a >> 1;       // token = assignment / TOPK
            hrof[a] = hr;
        }
    } else if (b < 1 + 1024) {
        int i = ((b - 1) * 256 + tid) * 4;
        float4 v = *(const float4*)(x + i);
        ushort4 o;
        o.x = f2bf(v.x); o.y = f2bf(v.y); o.z = f2bf(v.z); o.w = f2bf(v.w);
        *(ushort4*)(xbf + i) = o;
    } else {
        // w1 [E][HS=512][FFN=2048] -> w1T [E][FFN][HS]; 512 blocks:
        // e (8) x row-tile rbt (16) x col-quarter q (4), 16 col-tiles each
        int blk = b - 1025;
        int e = blk >> 6, rem = blk & 63;
        int rbt = rem >> 2, q = rem & 3;
        tr_strip(w1, w1T, HS, FFN, e, rbt * 32, q * 16, 16, tid, tsh);
    }
}

// ---- merged: GEMM1 (blocks 0..1279) + w2 strip-transpose (blocks 1280..1791) ----
// GEMM1: H[hr] = gelu(x[rowtok(hr)] @ w1T[e]), 128x64 tiles, K=512,
//        2-phase double-buffered global_load_lds pipeline (round-4 proven config).
__global__ __launch_bounds__(256) void k_g1w2t(
        const unsigned short* __restrict__ A,   // xbf
        const unsigned short* __restrict__ B,   // w1T
        unsigned short* __restrict__ Hout,
        const int* __restrict__ rowtok,
        const int* __restrict__ te, const int* __restrict__ tr,
        const float* __restrict__ w2, unsigned short* __restrict__ w2T) {
    __shared__ int4 smem4[49152 / 16];          // 48KB, shared by both paths
    int b = blockIdx.x;
    int tid = threadIdx.x;

    if (b >= 1280) {
        // w2 [E][FFN=2048][HS=512] -> w2T [E][HS][FFN]; 512 blocks:
        // e (8) x row-tile rbt (64), 16 col-tiles each
        int blk = b - 1280;
        int e = blk >> 6, rbt = blk & 63;
        tr_strip(w2, w2T, FFN, HS, e, rbt * 32, 0, 16, tid, (unsigned short*)smem4);
        return;
    }

    // ---- GEMM1 path: BM=128, BN=64, K=512 ----
    constexpr int BM = 128, BN = 64, K = HS;
    constexpr int MI = 4, NJ = 2, PA = 4, PB = 2;
    constexpr int ABYTES = BM * 64 * 2, BBYTES = BN * 64 * 2;  // 16KB, 8KB
    constexpr int NSTEP = K / 64;                               // 8
    constexpr int N = FFN;

    int ct = b & 31;            // 32 col tiles (FFN/64)
    int mt = b >> 5;            // 40 m tiles
    int e = te[mt];
    if (e < 0) return;
    int hr0 = tr[mt];

    char* A0 = (char*)smem4;
    char* A1 = A0 + ABYTES;
    char* B0 = A1 + ABYTES;
    char* B1 = B0 + BBYTES;

    int lane = tid & 63, wave = tid >> 6;
    int wm = wave >> 1, wn = wave & 1;

    // per-thread pre-swizzled global sources (chunk c8 of row r fetched from c8^(r&7))
    const char* asrc[PA];
    const char* bsrc[PB];
    int adoff[PA], bdoff[PB];
#pragma unroll
    for (int p = 0; p < PA; p++) {
        int idx = p * 256 + tid;
        int r = idx >> 3, c8 = idx & 7;
        int c8s = c8 ^ (r & 7);
        size_t row = (size_t)rowtok[hr0 + r];
        asrc[p] = (const char*)(A + row * K) + c8s * 16;
        adoff[p] = (p * 256 + wave * 64) * 16;
    }
#pragma unroll
    for (int p = 0; p < PB; p++) {
        int idx = p * 256 + tid;
        int r = idx >> 3, c8 = idx & 7;
        int c8s = c8 ^ (r & 7);
        bsrc[p] = (const char*)(B + ((size_t)e * N + (size_t)ct * BN + r) * K) + c8s * 16;
        bdoff[p] = (p * 256 + wave * 64) * 16;
    }

    f32x4 acc[MI][NJ] = {};

    auto stage = [&](char* Ad, char* Bd, int s) {
        int kb = s * 128;
#pragma unroll
        for (int p = 0; p < PA; p++) GLOAD16(asrc[p] + kb, Ad + adoff[p]);
#pragma unroll
        for (int p = 0; p < PB; p++) GLOAD16(bsrc[p] + kb, Bd + bdoff[p]);
    };
    auto compute = [&](const char* As, const char* Bs) {
#pragma unroll
        for (int kk = 0; kk < 64; kk += 32) {
            bf16x8 af[MI], bfv[NJ];
#pragma unroll
            for (int i = 0; i < MI; i++) {
                int ar = wm * (BM / 2) + i * 16 + (lane & 15);
                af[i] = *(const bf16x8*)(As + swz(ar, ar * 128 + kk * 2 + (lane >> 4) * 16));
            }
#pragma unroll
            for (int j = 0; j < NJ; j++) {
                int bc = wn * (BN / 2) + j * 16 + (lane & 15);
                bfv[j] = *(const bf16x8*)(Bs + swz(bc, bc * 128 + kk * 2 + (lane >> 4) * 16));
            }
#pragma unroll
            for (int i = 0; i < MI; i++)
#pragma unroll
                for (int j = 0; j < NJ; j++)
                    acc[i][j] = __builtin_amdgcn_mfma_f32_16x16x32_bf16(af[i], bfv[j], acc[i][j], 0, 0, 0);
        }
    };

    stage(A0, B0, 0);
    __syncthreads();
#pragma unroll 1
    for (int s = 0; s < NSTEP; s += 2) {
        if (s + 1 < NSTEP) stage(A1, B1, s + 1);
        compute(A0, B0);
        __syncthreads();
        if (s + 2 < NSTEP) stage(A0, B0, s + 2);
        compute(A1, B1);
        __syncthreads();
    }

    // epilogue: exact gelu, store bf16
#pragma unroll
    for (int i = 0; i < MI; i++)
#pragma unroll
        for (int j = 0; j < NJ; j++)
#pragma unroll
            for (int q = 0; q < 4; q++) {
                int row = hr0 + wm * (BM / 2) + i * 16 + (lane >> 4) * 4 + q;
                int col = ct * BN + wn * (BN / 2) + j * 16 + (lane & 15);
                float v = acc[i][j][q];
                float g = 0.5f * v * (1.0f + erff(v * 0.70710678118f));
                Hout[(size_t)row * N + col] = f2bf(g);
            }
}

// ---- GEMM2: split-K, 2-phase double-buffered pipeline ----
template<int BM, int BN, int KFULL, int KLOC>
__global__ __launch_bounds__(256) void k_gemm2(
        const unsigned short* __restrict__ A,
        const unsigned short* __restrict__ B,
        float* __restrict__ outp,
        const int* __restrict__ te, const int* __restrict__ tr, int N) {
    constexpr int MI = BM / 32, NJ = BN / 32;
    constexpr int PA = BM / 32, PB = BN / 32;
    constexpr int ABYTES = BM * 64 * 2, BBYTES = BN * 64 * 2;
    constexpr int NSTEP = KLOC / 64;
    static_assert(NSTEP % 2 == 0, "even steps");

    int mt = blockIdx.y;
    int e = te[mt];
    if (e < 0) return;
    int hr0 = tr[mt];
    int ct = blockIdx.x;
    int kz = blockIdx.z;
    int k0 = kz * KLOC;

    __shared__ int4 ldsv[(2 * (ABYTES + BBYTES)) / 16];
    char* A0 = (char*)ldsv;
    char* A1 = A0 + ABYTES;
    char* B0 = A1 + ABYTES;
    char* B1 = B0 + BBYTES;

    int tid = threadIdx.x;
    int lane = tid & 63, wave = tid >> 6;
    int wm = wave >> 1, wn = wave & 1;

    const char* asrc[PA];
    const char* bsrc[PB];
    int adoff[PA], bdoff[PB];
#pragma unroll
    for (int p = 0; p < PA; p++) {
        int idx = p * 256 + tid;
        int r = idx >> 3, c8 = idx & 7;
        int c8s = c8 ^ (r & 7);
        asrc[p] = (const char*)(A + (size_t)(hr0 + r) * KFULL + k0) + c8s * 16;
        adoff[p] = (p * 256 + wave * 64) * 16;
    }
#pragma unroll
    for (int p = 0; p < PB; p++) {
        int idx = p * 256 + tid;
        int r = idx >> 3, c8 = idx & 7;
        int c8s = c8 ^ (r & 7);
        bsrc[p] = (const char*)(B + ((size_t)e * N + (size_t)ct * BN + r) * KFULL + k0) + c8s * 16;
        bdoff[p] = (p * 256 + wave * 64) * 16;
    }

    f32x4 acc[MI][NJ] = {};

    auto stage = [&](char* Ad, char* Bd, int s) {
        int kb = s * 128;
#pragma unroll
        for (int p = 0; p < PA; p++) GLOAD16(asrc[p] + kb, Ad + adoff[p]);
#pragma unroll
        for (int p = 0; p < PB; p++) GLOAD16(bsrc[p] + kb, Bd + bdoff[p]);
    };
    auto compute = [&](const char* As, const char* Bs) {
#pragma unroll
        for (int kk = 0; kk < 64; kk += 32) {
            bf16x8 af[MI], bfv[NJ];
#pragma unroll
            for (int i = 0; i < MI; i++) {
                int ar = wm * (BM / 2) + i * 16 + (lane & 15);
                af[i] = *(const bf16x8*)(As + swz(ar, ar * 128 + kk * 2 + (lane >> 4) * 16));
            }
#pragma unroll
            for (int j = 0; j < NJ; j++) {
                int bc = wn * (BN / 2) + j * 16 + (lane & 15);
                bfv[j] = *(const bf16x8*)(Bs + swz(bc, bc * 128 + kk * 2 + (lane >> 4) * 16));
            }
#pragma unroll
            for (int i = 0; i < MI; i++)
#pragma unroll
                for (int j = 0; j < NJ; j++)
                    acc[i][j] = __builtin_amdgcn_mfma_f32_16x16x32_bf16(af[i], bfv[j], acc[i][j], 0, 0, 0);
        }
    };

    stage(A0, B0, 0);
    __syncthreads();
#pragma unroll 1
    for (int s = 0; s < NSTEP; s += 2) {
        if (s + 1 < NSTEP) stage(A1, B1, s + 1);
        compute(A0, B0);
        __syncthreads();
        if (s + 2 < NSTEP) stage(A0, B0, s + 2);
        compute(A1, B1);
        __syncthreads();
    }

    float* O = outp + (size_t)kz * PAD * HS;
#pragma unroll
    for (int i = 0; i < MI; i++)
#pragma unroll
        for (int j = 0; j < NJ; j++)
#pragma unroll
            for (int q = 0; q < 4; q++) {
                int row = hr0 + wm * (BM / 2) + i * 16 + (lane >> 4) * 4 + q;
                int col = ct * BN + wn * (BN / 2) + j * 16 + (lane & 15);
                O[(size_t)row * N + col] = acc[i][j][q];
            }
}

// ---- combine (float4): sum split-K partials; y[t] = w0*o0 + w1*o1 ;
//      buffer[t][0..7] fully written (zeros incl.) -> no memset anywhere ----
__global__ __launch_bounds__(256) void k_combine(
        const float4* __restrict__ outv, const int* __restrict__ ei,
        const float* __restrict__ ew, const int* __restrict__ hrof,
        float4* __restrict__ y, float4* __restrict__ buf) {
    constexpr int SPLIT_OFF = PAD * HS / 4;   // float4 stride between partials
    int g = blockIdx.x * 256 + threadIdx.x;   // over NTOK*HS/4
    int t = g >> 7, c4 = g & 127;             // HS/4 = 128
    int a0 = 2 * t, a1 = a0 + 1;
    int h0 = hrof[a0], h1 = hrof[a1];
    float4 p0a = outv[(size_t)h0 * (HS / 4) + c4];
    float4 p0b = outv[SPLIT_OFF + (size_t)h0 * (HS / 4) + c4];
    float4 p1a = outv[(size_t)h1 * (HS / 4) + c4];
    float4 p1b = outv[SPLIT_OFF + (size_t)h1 * (HS / 4) + c4];
    float4 o0 = make_float4(p0a.x + p0b.x, p0a.y + p0b.y, p0a.z + p0b.z, p0a.w + p0b.w);
    float4 o1 = make_float4(p1a.x + p1b.x, p1a.y + p1b.y, p1a.z + p1b.z, p1a.w + p1b.w);
    float w0 = ew[a0], w1 = ew[a1];
    y[g] = make_float4(w0 * o0.x + w1 * o1.x, w0 * o0.y + w1 * o1.y,
                       w0 * o0.z + w1 * o1.z, w0 * o0.w + w1 * o1.w);
    int e0 = ei[a0], e1 = ei[a1];
    size_t base = (size_t)t * (NE * HS / 4) + c4;
#pragma unroll
    for (int e = 0; e < NE; e++) {
        float4 v = make_float4(0.f, 0.f, 0.f, 0.f);
        if (e == e0) { v.x += o0.x; v.y += o0.y; v.z += o0.z; v.w += o0.w; }
        if (e == e1) { v.x += o1.x; v.y += o1.y; v.z += o1.z; v.w += o1.w; }
        buf[base + (size_t)e * (HS / 4)] = v;
    }
}

extern "C" void kernel_launch(void* const* d_in, const int* in_sizes, int n_in,
                              void* d_out, int out_size, void* d_ws, size_t ws_size,
                              hipStream_t stream) {
    const float* x  = (const float*)d_in[0];
    const float* ew = (const float*)d_in[1];
    const int*   ei = (const int*)d_in[2];
    const float* w1 = (const float*)d_in[3];
    const float* w2 = (const float*)d_in[4];

    char* ws = (char*)d_ws;
    unsigned short* xbf  = (unsigned short*)(ws + OFF_XBF);
    unsigned short* w1T  = (unsigned short*)(ws + OFF_W1T);
    unsigned short* w2T  = (unsigned short*)(ws + OFF_W2T);
    unsigned short* Hb   = (unsigned short*)(ws + OFF_H);
    float*          outv = (float*)(ws + OFF_OUTV);
    int*            rowtok = (int*)(ws + OFF_RT);
    int*            hrof   = (int*)(ws + OFF_HROF);
    int*            te128  = (int*)(ws + OFF_TE128);
    int*            tr128  = (int*)(ws + OFF_TR128);
    int*            te64   = (int*)(ws + OFF_TE64);
    int*            tr64   = (int*)(ws + OFF_TR64);

    float* y   = (float*)d_out;
    float* buf = (float*)d_out + (size_t)NTOK * HS;

    // prep1: setup + x->bf16 + w1 strip-transpose  (1 + 1024 + 512 blocks)
    k_prep1<<<1537, 256, 0, stream>>>(
        x, w1, ei, xbf, w1T, rowtok, hrof, te128, tr128, te64, tr64);
    // GEMM1 (1280 blocks, dispatched first) + w2 strip-transpose (512 blocks) in one launch
    k_g1w2t<<<1792, 256, 0, stream>>>(
        xbf, w1T, Hb, rowtok, te128, tr128, w2, w2T);
    // GEMM2 -> outv partials (f32): 64x64 tiles, split-K=2, grid 8 x 72 x 2 = 1152 blocks
    k_gemm2<64, 64, FFN, FFN / 2><<<dim3(HS / 64, MAXT64, 2), 256, 0, stream>>>(
        Hb, w2T, outv, te64, tr64, HS);
    // combine split-K partials into y and buffer (writes ALL buffer slots)
    k_combine<<<NTOK * HS / 4 / 256, 256, 0, stream>>>(
        (const float4*)outv, ei, ew, hrof, (float4*)y, (float4*)buf);
}

// Round 7
// 94.156 us; speedup vs baseline: 1.0744x; 1.0090x over previous
//
#include <hip/hip_runtime.h>
#include <hip/hip_bf16.h>

// Problem constants
#define NTOK 2048
#define TOPK 2
#define HS   512
#define FFN  2048
#define NE   8
#define TASSIGN (NTOK*TOPK)   // 4096
#define PAD  5120             // 4096 + 8*128
#define MAXT128 40
#define MAXT64  72

typedef __attribute__((ext_vector_type(8))) short bf16x8;
typedef __attribute__((ext_vector_type(8))) unsigned short u16x8;
typedef __attribute__((ext_vector_type(4))) float f32x4;

// ws layout (byte offsets); total ~67.15 MB
static const size_t OFF_XBF  = 0;            // [NTOK*HS] bf16
static const size_t OFF_W1T  = 2097152;      // [E][FFN][HS] bf16
static const size_t OFF_W2T  = 18874368;     // [E][HS][FFN] bf16
static const size_t OFF_H    = 35651584;     // [PAD][FFN] bf16
static const size_t OFF_OUTV = 56623104;     // [2][PAD][HS] bf16 (split-K partials)
static const size_t OFF_RT   = 67108864;     // rowtok [PAD] int
static const size_t OFF_HROF = 67129344;     // hrof [TASSIGN] int
static const size_t OFF_TE128= 67145728;
static const size_t OFF_TR128= 67145888;
static const size_t OFF_TE64 = 67146048;
static const size_t OFF_TR64 = 67146336;

__device__ __forceinline__ unsigned short f2bf(float f) {
    union { __hip_bfloat16 h; unsigned short u; } v;
    v.h = __float2bfloat16(f);
    return v.u;
}

__device__ __forceinline__ float bf2f(unsigned short u) {
    union { unsigned int i; float f; } v;
    v.i = ((unsigned int)u) << 16;
    return v.f;
}

__device__ __forceinline__ int swz(int r, int byte_off) {
    return byte_off ^ ((r & 7) << 4);
}

#define GLOAD16(gsrc, ldst) \
    __builtin_amdgcn_global_load_lds((const __attribute__((address_space(1))) void*)(gsrc), \
                                     (__attribute__((address_space(3))) void*)(ldst), 16, 0, 0)

// ---- strip transpose: in [E][R][C] f32 -> out [E][C][R] bf16, one 32-row strip,
//      ncb 32-col tiles starting at cb0 (LDS buffer passed in, 32*33 ushorts) ----
__device__ __forceinline__ void tr_strip(const float* __restrict__ in,
                                         unsigned short* __restrict__ out,
                                         int R, int C, int e, int rb, int cb0, int ncb,
                                         int tid, unsigned short* t) {
    int tx = tid & 31, ty = tid >> 5;          // 32 x 8
    const float* ip = in + (size_t)e * R * C;
    unsigned short* op = out + (size_t)e * C * R;
#pragma unroll 1
    for (int it = 0; it < ncb; ++it) {
        int cb = (cb0 + it) * 32;
        __syncthreads();
#pragma unroll
        for (int i = 0; i < 4; i++) {
            int r = ty + i * 8;
            t[r * 33 + tx] = f2bf(ip[(size_t)(rb + r) * C + cb + tx]);
        }
        __syncthreads();
#pragma unroll
        for (int i = 0; i < 4; i++) {
            int c = ty + i * 8;
            op[(size_t)(cb + c) * R + rb + tx] = t[tx * 33 + c];
        }
    }
}

// ---- prep1: setup (block 0) + x->bf16 (1024) + w1 strip-transpose (512) ----
__global__ __launch_bounds__(256) void k_prep1(
        const float* __restrict__ x, const float* __restrict__ w1,
        const int* __restrict__ ei,
        unsigned short* __restrict__ xbf, unsigned short* __restrict__ w1T,
        int* __restrict__ rowtok, int* __restrict__ hrof,
        int* __restrict__ te128, int* __restrict__ tr128,
        int* __restrict__ te64, int* __restrict__ tr64) {
    __shared__ unsigned short tsh[32 * 33];
    int b = blockIdx.x;
    int tid = threadIdx.x;
    if (b == 0) {
        // setup: counting sort by expert, 128-padded segments, two tile tables
        __shared__ int cnt[NE], offpad[NE], cur[NE];
        for (int i = tid; i < PAD; i += 256) rowtok[i] = 0;   // pad rows -> token 0 (harmless)
        if (tid < NE) cnt[tid] = 0;
        __syncthreads();
        for (int a = tid; a < TASSIGN; a += 256) atomicAdd(&cnt[ei[a]], 1);
        __syncthreads();
        if (tid == 0) {
            int o = 0, t1 = 0, t2 = 0;
            for (int e = 0; e < NE; e++) {
                offpad[e] = o; cur[e] = 0;
                for (int r = 0; r < cnt[e]; r += 128) { te128[t1] = e; tr128[t1] = o + r; t1++; }
                for (int r = 0; r < cnt[e]; r += 64)  { te64[t2]  = e; tr64[t2]  = o + r; t2++; }
                o += (cnt[e] + 127) / 128 * 128;
            }
            for (; t1 < MAXT128; t1++) te128[t1] = -1;
            for (; t2 < MAXT64;  t2++) te64[t2]  = -1;
        }
        __syncthreads();
        for (int a = tid; a < TASSIGN; a += 256) {
            int e = ei[a];
            int r = atomicAdd(&cur[e], 1);
            int hr = offpad[e] + r;
            rowtok[hr] = a >> 1;       // token = assignment / TOPK
            hrof[a] = hr;
        }
    } else if (b < 1 + 1024) {
        int i = ((b - 1) * 256 + tid) * 4;
        float4 v = *(const float4*)(x + i);
        ushort4 o;
        o.x = f2bf(v.x); o.y = f2bf(v.y); o.z = f2bf(v.z); o.w = f2bf(v.w);
        *(ushort4*)(xbf + i) = o;
    } else {
        // w1 [E][HS=512][FFN=2048] -> w1T [E][FFN][HS]; 512 blocks:
        // e (8) x row-tile rbt (16) x col-quarter q (4), 16 col-tiles each
        int blk = b - 1025;
        int e = blk >> 6, rem = blk & 63;
        int rbt = rem >> 2, q = rem & 3;
        tr_strip(w1, w1T, HS, FFN, e, rbt * 32, q * 16, 16, tid, tsh);
    }
}

// ---- merged: w2 strip-transpose (blocks 0..511, dispatched FIRST so it overlaps
//      the GEMM's idle bandwidth) + GEMM1 (blocks 512..1791) ----
// GEMM1: H[hr] = gelu(x[rowtok(hr)] @ w1T[e]), 128x64 tiles, K=512,
//        2-phase double-buffered global_load_lds pipeline (round-4 proven config).
__global__ __launch_bounds__(256) void k_g1w2t(
        const unsigned short* __restrict__ A,   // xbf
        const unsigned short* __restrict__ B,   // w1T
        unsigned short* __restrict__ Hout,
        const int* __restrict__ rowtok,
        const int* __restrict__ te, const int* __restrict__ tr,
        const float* __restrict__ w2, unsigned short* __restrict__ w2T) {
    __shared__ int4 smem4[49152 / 16];          // 48KB, shared by both paths
    int b = blockIdx.x;
    int tid = threadIdx.x;

    if (b < 512) {
        // w2 [E][FFN=2048][HS=512] -> w2T [E][HS][FFN]; 512 blocks:
        // e (8) x row-tile rbt (64), 16 col-tiles each
        int e = b >> 6, rbt = b & 63;
        tr_strip(w2, w2T, FFN, HS, e, rbt * 32, 0, 16, tid, (unsigned short*)smem4);
        return;
    }

    // ---- GEMM1 path: BM=128, BN=64, K=512 ----
    constexpr int BM = 128, BN = 64, K = HS;
    constexpr int MI = 4, NJ = 2, PA = 4, PB = 2;
    constexpr int ABYTES = BM * 64 * 2, BBYTES = BN * 64 * 2;  // 16KB, 8KB
    constexpr int NSTEP = K / 64;                               // 8
    constexpr int N = FFN;

    int bb = b - 512;
    int ct = bb & 31;            // 32 col tiles (FFN/64)
    int mt = bb >> 5;            // 40 m tiles
    int e = te[mt];
    if (e < 0) return;
    int hr0 = tr[mt];

    char* A0 = (char*)smem4;
    char* A1 = A0 + ABYTES;
    char* B0 = A1 + ABYTES;
    char* B1 = B0 + BBYTES;

    int lane = tid & 63, wave = tid >> 6;
    int wm = wave >> 1, wn = wave & 1;

    // per-thread pre-swizzled global sources (chunk c8 of row r fetched from c8^(r&7))
    const char* asrc[PA];
    const char* bsrc[PB];
    int adoff[PA], bdoff[PB];
#pragma unroll
    for (int p = 0; p < PA; p++) {
        int idx = p * 256 + tid;
        int r = idx >> 3, c8 = idx & 7;
        int c8s = c8 ^ (r & 7);
        size_t row = (size_t)rowtok[hr0 + r];
        asrc[p] = (const char*)(A + row * K) + c8s * 16;
        adoff[p] = (p * 256 + wave * 64) * 16;
    }
#pragma unroll
    for (int p = 0; p < PB; p++) {
        int idx = p * 256 + tid;
        int r = idx >> 3, c8 = idx & 7;
        int c8s = c8 ^ (r & 7);
        bsrc[p] = (const char*)(B + ((size_t)e * N + (size_t)ct * BN + r) * K) + c8s * 16;
        bdoff[p] = (p * 256 + wave * 64) * 16;
    }

    f32x4 acc[MI][NJ] = {};

    auto stage = [&](char* Ad, char* Bd, int s) {
        int kb = s * 128;
#pragma unroll
        for (int p = 0; p < PA; p++) GLOAD16(asrc[p] + kb, Ad + adoff[p]);
#pragma unroll
        for (int p = 0; p < PB; p++) GLOAD16(bsrc[p] + kb, Bd + bdoff[p]);
    };
    auto compute = [&](const char* As, const char* Bs) {
#pragma unroll
        for (int kk = 0; kk < 64; kk += 32) {
            bf16x8 af[MI], bfv[NJ];
#pragma unroll
            for (int i = 0; i < MI; i++) {
                int ar = wm * (BM / 2) + i * 16 + (lane & 15);
                af[i] = *(const bf16x8*)(As + swz(ar, ar * 128 + kk * 2 + (lane >> 4) * 16));
            }
#pragma unroll
            for (int j = 0; j < NJ; j++) {
                int bc = wn * (BN / 2) + j * 16 + (lane & 15);
                bfv[j] = *(const bf16x8*)(Bs + swz(bc, bc * 128 + kk * 2 + (lane >> 4) * 16));
            }
#pragma unroll
            for (int i = 0; i < MI; i++)
#pragma unroll
                for (int j = 0; j < NJ; j++)
                    acc[i][j] = __builtin_amdgcn_mfma_f32_16x16x32_bf16(af[i], bfv[j], acc[i][j], 0, 0, 0);
        }
    };

    stage(A0, B0, 0);
    __syncthreads();
#pragma unroll 1
    for (int s = 0; s < NSTEP; s += 2) {
        if (s + 1 < NSTEP) stage(A1, B1, s + 1);
        compute(A0, B0);
        __syncthreads();
        if (s + 2 < NSTEP) stage(A0, B0, s + 2);
        compute(A1, B1);
        __syncthreads();
    }

    // epilogue: exact gelu, store bf16
#pragma unroll
    for (int i = 0; i < MI; i++)
#pragma unroll
        for (int j = 0; j < NJ; j++)
#pragma unroll
            for (int q = 0; q < 4; q++) {
                int row = hr0 + wm * (BM / 2) + i * 16 + (lane >> 4) * 4 + q;
                int col = ct * BN + wn * (BN / 2) + j * 16 + (lane & 15);
                float v = acc[i][j][q];
                float g = 0.5f * v * (1.0f + erff(v * 0.70710678118f));
                Hout[(size_t)row * N + col] = f2bf(g);
            }
}

// ---- GEMM2: split-K=2, 2-phase double-buffered pipeline, bf16 partial outputs ----
template<int BM, int BN, int KFULL, int KLOC>
__global__ __launch_bounds__(256) void k_gemm2(
        const unsigned short* __restrict__ A,
        const unsigned short* __restrict__ B,
        unsigned short* __restrict__ outp,
        const int* __restrict__ te, const int* __restrict__ tr, int N) {
    constexpr int MI = BM / 32, NJ = BN / 32;
    constexpr int PA = BM / 32, PB = BN / 32;
    constexpr int ABYTES = BM * 64 * 2, BBYTES = BN * 64 * 2;
    constexpr int NSTEP = KLOC / 64;
    static_assert(NSTEP % 2 == 0, "even steps");

    int mt = blockIdx.y;
    int e = te[mt];
    if (e < 0) return;
    int hr0 = tr[mt];
    int ct = blockIdx.x;
    int kz = blockIdx.z;
    int k0 = kz * KLOC;

    __shared__ int4 ldsv[(2 * (ABYTES + BBYTES)) / 16];
    char* A0 = (char*)ldsv;
    char* A1 = A0 + ABYTES;
    char* B0 = A1 + ABYTES;
    char* B1 = B0 + BBYTES;

    int tid = threadIdx.x;
    int lane = tid & 63, wave = tid >> 6;
    int wm = wave >> 1, wn = wave & 1;

    const char* asrc[PA];
    const char* bsrc[PB];
    int adoff[PA], bdoff[PB];
#pragma unroll
    for (int p = 0; p < PA; p++) {
        int idx = p * 256 + tid;
        int r = idx >> 3, c8 = idx & 7;
        int c8s = c8 ^ (r & 7);
        asrc[p] = (const char*)(A + (size_t)(hr0 + r) * KFULL + k0) + c8s * 16;
        adoff[p] = (p * 256 + wave * 64) * 16;
    }
#pragma unroll
    for (int p = 0; p < PB; p++) {
        int idx = p * 256 + tid;
        int r = idx >> 3, c8 = idx & 7;
        int c8s = c8 ^ (r & 7);
        bsrc[p] = (const char*)(B + ((size_t)e * N + (size_t)ct * BN + r) * KFULL + k0) + c8s * 16;
        bdoff[p] = (p * 256 + wave * 64) * 16;
    }

    f32x4 acc[MI][NJ] = {};

    auto stage = [&](char* Ad, char* Bd, int s) {
        int kb = s * 128;
#pragma unroll
        for (int p = 0; p < PA; p++) GLOAD16(asrc[p] + kb, Ad + adoff[p]);
#pragma unroll
        for (int p = 0; p < PB; p++) GLOAD16(bsrc[p] + kb, Bd + bdoff[p]);
    };
    auto compute = [&](const char* As, const char* Bs) {
#pragma unroll
        for (int kk = 0; kk < 64; kk += 32) {
            bf16x8 af[MI], bfv[NJ];
#pragma unroll
            for (int i = 0; i < MI; i++) {
                int ar = wm * (BM / 2) + i * 16 + (lane & 15);
                af[i] = *(const bf16x8*)(As + swz(ar, ar * 128 + kk * 2 + (lane >> 4) * 16));
            }
#pragma unroll
            for (int j = 0; j < NJ; j++) {
                int bc = wn * (BN / 2) + j * 16 + (lane & 15);
                bfv[j] = *(const bf16x8*)(Bs + swz(bc, bc * 128 + kk * 2 + (lane >> 4) * 16));
            }
#pragma unroll
            for (int i = 0; i < MI; i++)
#pragma unroll
                for (int j = 0; j < NJ; j++)
                    acc[i][j] = __builtin_amdgcn_mfma_f32_16x16x32_bf16(af[i], bfv[j], acc[i][j], 0, 0, 0);
        }
    };

    stage(A0, B0, 0);
    __syncthreads();
#pragma unroll 1
    for (int s = 0; s < NSTEP; s += 2) {
        if (s + 1 < NSTEP) stage(A1, B1, s + 1);
        compute(A0, B0);
        __syncthreads();
        if (s + 2 < NSTEP) stage(A0, B0, s + 2);
        compute(A1, B1);
        __syncthreads();
    }

    unsigned short* O = outp + (size_t)kz * PAD * HS;
#pragma unroll
    for (int i = 0; i < MI; i++)
#pragma unroll
        for (int j = 0; j < NJ; j++)
#pragma unroll
            for (int q = 0; q < 4; q++) {
                int row = hr0 + wm * (BM / 2) + i * 16 + (lane >> 4) * 4 + q;
                int col = ct * BN + wn * (BN / 2) + j * 16 + (lane & 15);
                O[(size_t)row * N + col] = f2bf(acc[i][j][q]);
            }
}

// ---- combine: sum bf16 split-K partials; y[t] = w0*o0 + w1*o1 ;
//      buffer[t][0..7] fully written (zeros incl.) -> no memset anywhere.
//      One wave handles one full token row (64 lanes x 8 cols = 512). ----
__global__ __launch_bounds__(256) void k_combine(
        const unsigned short* __restrict__ outv, const int* __restrict__ ei,
        const float* __restrict__ ew, const int* __restrict__ hrof,
        float* __restrict__ y, float* __restrict__ buf) {
    constexpr size_t SPLIT = (size_t)PAD * HS;   // elements between partials
    int g = blockIdx.x * 256 + threadIdx.x;      // over NTOK*HS/8
    int t = g >> 6, c8 = g & 63;                 // HS/8 = 64 chunks/token
    int a0 = 2 * t, a1 = a0 + 1;
    int h0 = hrof[a0], h1 = hrof[a1];
    u16x8 q0a = *(const u16x8*)(outv + (size_t)h0 * HS + c8 * 8);
    u16x8 q0b = *(const u16x8*)(outv + SPLIT + (size_t)h0 * HS + c8 * 8);
    u16x8 q1a = *(const u16x8*)(outv + (size_t)h1 * HS + c8 * 8);
    u16x8 q1b = *(const u16x8*)(outv + SPLIT + (size_t)h1 * HS + c8 * 8);
    float w0 = ew[a0], w1 = ew[a1];
    float o0[8], o1[8], yy[8];
#pragma unroll
    for (int k = 0; k < 8; k++) {
        o0[k] = bf2f(q0a[k]) + bf2f(q0b[k]);
        o1[k] = bf2f(q1a[k]) + bf2f(q1b[k]);
        yy[k] = w0 * o0[k] + w1 * o1[k];
    }
    float* yp = y + (size_t)t * HS + c8 * 8;
    *(float4*)(yp)     = make_float4(yy[0], yy[1], yy[2], yy[3]);
    *(float4*)(yp + 4) = make_float4(yy[4], yy[5], yy[6], yy[7]);
    int e0 = ei[a0], e1 = ei[a1];
    float* bt = buf + (size_t)t * (NE * HS) + c8 * 8;
#pragma unroll
    for (int e = 0; e < NE; e++) {
        float v[8];
#pragma unroll
        for (int k = 0; k < 8; k++)
            v[k] = (e == e0 ? o0[k] : 0.0f) + (e == e1 ? o1[k] : 0.0f);
        float* be = bt + (size_t)e * HS;
        *(float4*)(be)     = make_float4(v[0], v[1], v[2], v[3]);
        *(float4*)(be + 4) = make_float4(v[4], v[5], v[6], v[7]);
    }
}

extern "C" void kernel_launch(void* const* d_in, const int* in_sizes, int n_in,
                              void* d_out, int out_size, void* d_ws, size_t ws_size,
                              hipStream_t stream) {
    const float* x  = (const float*)d_in[0];
    const float* ew = (const float*)d_in[1];
    const int*   ei = (const int*)d_in[2];
    const float* w1 = (const float*)d_in[3];
    const float* w2 = (const float*)d_in[4];

    char* ws = (char*)d_ws;
    unsigned short* xbf  = (unsigned short*)(ws + OFF_XBF);
    unsigned short* w1T  = (unsigned short*)(ws + OFF_W1T);
    unsigned short* w2T  = (unsigned short*)(ws + OFF_W2T);
    unsigned short* Hb   = (unsigned short*)(ws + OFF_H);
    unsigned short* outv = (unsigned short*)(ws + OFF_OUTV);
    int*            rowtok = (int*)(ws + OFF_RT);
    int*            hrof   = (int*)(ws + OFF_HROF);
    int*            te128  = (int*)(ws + OFF_TE128);
    int*            tr128  = (int*)(ws + OFF_TR128);
    int*            te64   = (int*)(ws + OFF_TE64);
    int*            tr64   = (int*)(ws + OFF_TR64);

    float* y   = (float*)d_out;
    float* buf = (float*)d_out + (size_t)NTOK * HS;

    // prep1: setup + x->bf16 + w1 strip-transpose  (1 + 1024 + 512 blocks)
    k_prep1<<<1537, 256, 0, stream>>>(
        x, w1, ei, xbf, w1T, rowtok, hrof, te128, tr128, te64, tr64);
    // w2 strip-transpose (512 blocks, FIRST) + GEMM1 (1280 blocks) in one launch
    k_g1w2t<<<1792, 256, 0, stream>>>(
        xbf, w1T, Hb, rowtok, te128, tr128, w2, w2T);
    // GEMM2 -> bf16 outv partials: 64x64 tiles, split-K=2, grid 8 x 72 x 2 = 1152 blocks
    k_gemm2<64, 64, FFN, FFN / 2><<<dim3(HS / 64, MAXT64, 2), 256, 0, stream>>>(
        Hb, w2T, outv, te64, tr64, HS);
    // combine split-K partials into y and buffer (writes ALL buffer slots)
    k_combine<<<NTOK * HS / 8 / 256, 256, 0, stream>>>(
        outv, ei, ew, hrof, y, buf);
}

// Round 8
// 88.646 us; speedup vs baseline: 1.1412x; 1.0622x over previous
//
#include <hip/hip_runtime.h>
#include <hip/hip_bf16.h>

// Problem constants
#define NTOK 2048
#define TOPK 2
#define HS   512
#define FFN  2048
#define NE   8
#define TASSIGN (NTOK*TOPK)   // 4096
#define PAD  5120             // 4096 + 8*128
#define MAXT128 40
#define MAXT64  72

typedef __attribute__((ext_vector_type(8))) short bf16x8;
typedef __attribute__((ext_vector_type(8))) unsigned short u16x8;
typedef __attribute__((ext_vector_type(4))) float f32x4;

// ws layout (byte offsets); total ~67.15 MB
static const size_t OFF_XBF  = 0;            // [NTOK*HS] bf16
static const size_t OFF_W1T  = 2097152;      // [E][FFN][HS] bf16
static const size_t OFF_W2T  = 18874368;     // [E][HS][FFN] bf16
static const size_t OFF_H    = 35651584;     // [PAD][FFN] bf16
static const size_t OFF_OUTV = 56623104;     // [2][PAD][HS] bf16 (split-K partials)
static const size_t OFF_RT   = 67108864;     // rowtok [PAD] int
static const size_t OFF_HROF = 67129344;     // hrof [TASSIGN] int
static const size_t OFF_TE128= 67145728;
static const size_t OFF_TR128= 67145888;
static const size_t OFF_TE64 = 67146048;
static const size_t OFF_TR64 = 67146336;

__device__ __forceinline__ unsigned short f2bf(float f) {
    union { __hip_bfloat16 h; unsigned short u; } v;
    v.h = __float2bfloat16(f);
    return v.u;
}

__device__ __forceinline__ float bf2f(unsigned short u) {
    union { unsigned int i; float f; } v;
    v.i = ((unsigned int)u) << 16;
    return v.f;
}

__device__ __forceinline__ int swz(int r, int byte_off) {
    return byte_off ^ ((r & 7) << 4);
}

// tanh-approx GELU = x*sigmoid(x*(1.59577 + 0.0713548*x^2)); |err| < 5e-4.
// exp overflow-safe: e=inf -> x - x/inf = x; e~0 -> x - x/1 = 0.
__device__ __forceinline__ float gelu_fast(float x) {
    float z2 = x * fmaf(0.0713548162726f, x * x, 1.5957691216057f);
    float e = __expf(z2);
    return x - __fdividef(x, e + 1.0f);
}

#define GLOAD16(gsrc, ldst) \
    __builtin_amdgcn_global_load_lds((const __attribute__((address_space(1))) void*)(gsrc), \
                                     (__attribute__((address_space(3))) void*)(ldst), 16, 0, 0)

// ---- fused prep (R4-proven): setup (block 0) + x->bf16 (1024) + w1T (8192) + w2T (8192) ----
__device__ __forceinline__ void dev_transpose(const float* __restrict__ in,
                                              unsigned short* __restrict__ out,
                                              int R, int C, int e, int rb, int cb, int tid) {
    __shared__ unsigned short t[32][33];
    int tx = tid & 31, ty = tid >> 5;          // 32 x 8
    const float* ip = in + (size_t)e * R * C;
    unsigned short* op = out + (size_t)e * C * R;
#pragma unroll
    for (int i = 0; i < 4; i++) {
        int r = ty + i * 8;
        t[r][tx] = f2bf(ip[(size_t)(rb + r) * C + cb + tx]);
    }
    __syncthreads();
#pragma unroll
    for (int i = 0; i < 4; i++) {
        int c = ty + i * 8;
        op[(size_t)(cb + c) * R + rb + tx] = t[tx][c];
    }
}

__global__ __launch_bounds__(256) void k_prep(
        const float* __restrict__ x, const float* __restrict__ w1,
        const float* __restrict__ w2, const int* __restrict__ ei,
        unsigned short* __restrict__ xbf, unsigned short* __restrict__ w1T,
        unsigned short* __restrict__ w2T,
        int* __restrict__ rowtok, int* __restrict__ hrof,
        int* __restrict__ te128, int* __restrict__ tr128,
        int* __restrict__ te64, int* __restrict__ tr64) {
    int b = blockIdx.x;
    int tid = threadIdx.x;
    if (b == 0) {
        // setup: counting sort by expert, 128-padded segments, two tile tables
        __shared__ int cnt[NE], offpad[NE], cur[NE];
        for (int i = tid; i < PAD; i += 256) rowtok[i] = 0;   // pad rows -> token 0 (harmless)
        if (tid < NE) cnt[tid] = 0;
        __syncthreads();
        for (int a = tid; a < TASSIGN; a += 256) atomicAdd(&cnt[ei[a]], 1);
        __syncthreads();
        if (tid == 0) {
            int o = 0, t1 = 0, t2 = 0;
            for (int e = 0; e < NE; e++) {
                offpad[e] = o; cur[e] = 0;
                for (int r = 0; r < cnt[e]; r += 128) { te128[t1] = e; tr128[t1] = o + r; t1++; }
                for (int r = 0; r < cnt[e]; r += 64)  { te64[t2]  = e; tr64[t2]  = o + r; t2++; }
                o += (cnt[e] + 127) / 128 * 128;
            }
            for (; t1 < MAXT128; t1++) te128[t1] = -1;
            for (; t2 < MAXT64;  t2++) te64[t2]  = -1;
        }
        __syncthreads();
        for (int a = tid; a < TASSIGN; a += 256) {
            int e = ei[a];
            int r = atomicAdd(&cur[e], 1);
            int hr = offpad[e] + r;
            rowtok[hr] = a >> 1;       // token = assignment / TOPK
            hrof[a] = hr;
        }
    } else if (b < 1 + 1024) {
        int i = ((b - 1) * 256 + tid) * 4;
        float4 v = *(const float4*)(x + i);
        ushort4 o;
        o.x = f2bf(v.x); o.y = f2bf(v.y); o.z = f2bf(v.z); o.w = f2bf(v.w);
        *(ushort4*)(xbf + i) = o;
    } else if (b < 1 + 1024 + 8192) {
        // w1 [E][HS][FFN] -> w1T [E][FFN][HS]: R=HS, C=FFN
        int blk = b - 1025;
        int e = blk >> 10, rem = blk & 1023;
        dev_transpose(w1, w1T, HS, FFN, e, (rem >> 6) * 32, (rem & 63) * 32, tid);
    } else {
        // w2 [E][FFN][HS] -> w2T [E][HS][FFN]: R=FFN, C=HS
        int blk = b - 9217;
        int e = blk >> 10, rem = blk & 1023;
        dev_transpose(w2, w2T, FFN, HS, e, (rem >> 4) * 32, (rem & 15) * 32, tid);
    }
}

// ---- grouped GEMM: 2-phase double-buffered global_load_lds pipeline ----
// G1=true:  H = gelu_fast(A_gathered @ B^T-layout), bf16 out (kz unused)
// G1=false: bf16 split-K partials, blockIdx.z selects K-slice
template<int BM, int BN, int KFULL, int KLOC, bool G1>
__global__ __launch_bounds__(256) void k_gemm(
        const unsigned short* __restrict__ A,
        const unsigned short* __restrict__ B,
        unsigned short* __restrict__ outp,
        const int* __restrict__ rowtok,
        const int* __restrict__ te, const int* __restrict__ tr, int N) {
    constexpr int MI = BM / 32, NJ = BN / 32;
    constexpr int PA = BM / 32, PB = BN / 32;       // gload sets of 256 lanes x 16B
    constexpr int ABYTES = BM * 64 * 2, BBYTES = BN * 64 * 2;
    constexpr int NSTEP = KLOC / 64;
    static_assert(NSTEP % 2 == 0, "even steps");

    int mt = blockIdx.y;
    int e = te[mt];
    if (e < 0) return;
    int hr0 = tr[mt];
    int ct = blockIdx.x;
    int kz = blockIdx.z;
    int k0 = kz * KLOC;

    __shared__ int4 ldsv[(2 * (ABYTES + BBYTES)) / 16];
    char* A0 = (char*)ldsv;
    char* A1 = A0 + ABYTES;
    char* B0 = A1 + ABYTES;
    char* B1 = B0 + BBYTES;

    int tid = threadIdx.x;
    int lane = tid & 63, wave = tid >> 6;
    int wm = wave >> 1, wn = wave & 1;

    // per-thread pre-swizzled global sources (chunk c8 of row r fetched from c8^(r&7))
    const char* asrc[PA];
    const char* bsrc[PB];
    int adoff[PA], bdoff[PB];
#pragma unroll
    for (int p = 0; p < PA; p++) {
        int idx = p * 256 + tid;
        int r = idx >> 3, c8 = idx & 7;
        int c8s = c8 ^ (r & 7);
        size_t row = G1 ? (size_t)rowtok[hr0 + r] : (size_t)(hr0 + r);
        asrc[p] = (const char*)(A + row * KFULL + k0) + c8s * 16;
        adoff[p] = (p * 256 + wave * 64) * 16;      // wave-uniform linear LDS dest
    }
#pragma unroll
    for (int p = 0; p < PB; p++) {
        int idx = p * 256 + tid;
        int r = idx >> 3, c8 = idx & 7;
        int c8s = c8 ^ (r & 7);
        bsrc[p] = (const char*)(B + ((size_t)e * N + (size_t)ct * BN + r) * KFULL + k0) + c8s * 16;
        bdoff[p] = (p * 256 + wave * 64) * 16;
    }

    f32x4 acc[MI][NJ] = {};

    auto stage = [&](char* Ad, char* Bd, int s) {
        int kb = s * 128;                            // 64 k-elems * 2B
#pragma unroll
        for (int p = 0; p < PA; p++) GLOAD16(asrc[p] + kb, Ad + adoff[p]);
#pragma unroll
        for (int p = 0; p < PB; p++) GLOAD16(bsrc[p] + kb, Bd + bdoff[p]);
    };
    auto compute = [&](const char* As, const char* Bs) {
#pragma unroll
        for (int kk = 0; kk < 64; kk += 32) {
            bf16x8 af[MI], bfv[NJ];
#pragma unroll
            for (int i = 0; i < MI; i++) {
                int ar = wm * (BM / 2) + i * 16 + (lane & 15);
                af[i] = *(const bf16x8*)(As + swz(ar, ar * 128 + kk * 2 + (lane >> 4) * 16));
            }
#pragma unroll
            for (int j = 0; j < NJ; j++) {
                int bc = wn * (BN / 2) + j * 16 + (lane & 15);
                bfv[j] = *(const bf16x8*)(Bs + swz(bc, bc * 128 + kk * 2 + (lane >> 4) * 16));
            }
#pragma unroll
            for (int i = 0; i < MI; i++)
#pragma unroll
                for (int j = 0; j < NJ; j++)
                    acc[i][j] = __builtin_amdgcn_mfma_f32_16x16x32_bf16(af[i], bfv[j], acc[i][j], 0, 0, 0);
        }
    };

    // prologue
    stage(A0, B0, 0);
    __syncthreads();                                 // buf0 ready
    // 2-phase pipeline: issue next-step loads before computing current step;
    // the single __syncthreads per step drains them only AFTER compute.
#pragma unroll 1
    for (int s = 0; s < NSTEP; s += 2) {
        if (s + 1 < NSTEP) stage(A1, B1, s + 1);
        compute(A0, B0);
        __syncthreads();
        if (s + 2 < NSTEP) stage(A0, B0, s + 2);
        compute(A1, B1);
        __syncthreads();
    }

    if constexpr (G1) {
#pragma unroll
        for (int i = 0; i < MI; i++)
#pragma unroll
            for (int j = 0; j < NJ; j++)
#pragma unroll
                for (int q = 0; q < 4; q++) {
                    int row = hr0 + wm * (BM / 2) + i * 16 + (lane >> 4) * 4 + q;
                    int col = ct * BN + wn * (BN / 2) + j * 16 + (lane & 15);
                    outp[(size_t)row * N + col] = f2bf(gelu_fast(acc[i][j][q]));
                }
    } else {
        unsigned short* O = outp + (size_t)kz * PAD * HS;
#pragma unroll
        for (int i = 0; i < MI; i++)
#pragma unroll
            for (int j = 0; j < NJ; j++)
#pragma unroll
                for (int q = 0; q < 4; q++) {
                    int row = hr0 + wm * (BM / 2) + i * 16 + (lane >> 4) * 4 + q;
                    int col = ct * BN + wn * (BN / 2) + j * 16 + (lane & 15);
                    O[(size_t)row * N + col] = f2bf(acc[i][j][q]);
                }
    }
}

// ---- combine: sum bf16 split-K partials; y[t] = w0*o0 + w1*o1 ;
//      buffer[t][0..7] fully written (zeros incl.) -> no memset anywhere. ----
__global__ __launch_bounds__(256) void k_combine(
        const unsigned short* __restrict__ outv, const int* __restrict__ ei,
        const float* __restrict__ ew, const int* __restrict__ hrof,
        float* __restrict__ y, float* __restrict__ buf) {
    constexpr size_t SPLIT = (size_t)PAD * HS;   // elements between partials
    int g = blockIdx.x * 256 + threadIdx.x;      // over NTOK*HS/8
    int t = g >> 6, c8 = g & 63;                 // HS/8 = 64 chunks/token
    int a0 = 2 * t, a1 = a0 + 1;
    int h0 = hrof[a0], h1 = hrof[a1];
    u16x8 q0a = *(const u16x8*)(outv + (size_t)h0 * HS + c8 * 8);
    u16x8 q0b = *(const u16x8*)(outv + SPLIT + (size_t)h0 * HS + c8 * 8);
    u16x8 q1a = *(const u16x8*)(outv + (size_t)h1 * HS + c8 * 8);
    u16x8 q1b = *(const u16x8*)(outv + SPLIT + (size_t)h1 * HS + c8 * 8);
    float w0 = ew[a0], w1 = ew[a1];
    float o0[8], o1[8], yy[8];
#pragma unroll
    for (int k = 0; k < 8; k++) {
        o0[k] = bf2f(q0a[k]) + bf2f(q0b[k]);
        o1[k] = bf2f(q1a[k]) + bf2f(q1b[k]);
        yy[k] = w0 * o0[k] + w1 * o1[k];
    }
    float* yp = y + (size_t)t * HS + c8 * 8;
    *(float4*)(yp)     = make_float4(yy[0], yy[1], yy[2], yy[3]);
    *(float4*)(yp + 4) = make_float4(yy[4], yy[5], yy[6], yy[7]);
    int e0 = ei[a0], e1 = ei[a1];
    float* bt = buf + (size_t)t * (NE * HS) + c8 * 8;
#pragma unroll
    for (int e = 0; e < NE; e++) {
        float v[8];
#pragma unroll
        for (int k = 0; k < 8; k++)
            v[k] = (e == e0 ? o0[k] : 0.0f) + (e == e1 ? o1[k] : 0.0f);
        float* be = bt + (size_t)e * HS;
        *(float4*)(be)     = make_float4(v[0], v[1], v[2], v[3]);
        *(float4*)(be + 4) = make_float4(v[4], v[5], v[6], v[7]);
    }
}

extern "C" void kernel_launch(void* const* d_in, const int* in_sizes, int n_in,
                              void* d_out, int out_size, void* d_ws, size_t ws_size,
                              hipStream_t stream) {
    const float* x  = (const float*)d_in[0];
    const float* ew = (const float*)d_in[1];
    const int*   ei = (const int*)d_in[2];
    const float* w1 = (const float*)d_in[3];
    const float* w2 = (const float*)d_in[4];

    char* ws = (char*)d_ws;
    unsigned short* xbf  = (unsigned short*)(ws + OFF_XBF);
    unsigned short* w1T  = (unsigned short*)(ws + OFF_W1T);
    unsigned short* w2T  = (unsigned short*)(ws + OFF_W2T);
    unsigned short* Hb   = (unsigned short*)(ws + OFF_H);
    unsigned short* outv = (unsigned short*)(ws + OFF_OUTV);
    int*            rowtok = (int*)(ws + OFF_RT);
    int*            hrof   = (int*)(ws + OFF_HROF);
    int*            te128  = (int*)(ws + OFF_TE128);
    int*            tr128  = (int*)(ws + OFF_TR128);
    int*            te64   = (int*)(ws + OFF_TE64);
    int*            tr64   = (int*)(ws + OFF_TR64);

    float* y   = (float*)d_out;
    float* buf = (float*)d_out + (size_t)NTOK * HS;

    // fused prep (R4-proven): setup + xcvt + both weight transposes, one launch
    k_prep<<<1 + 1024 + 8192 + 8192, 256, 0, stream>>>(
        x, w1, w2, ei, xbf, w1T, w2T, rowtok, hrof, te128, tr128, te64, tr64);
    // GEMM1 + fast gelu -> H (bf16): 128x64 tiles, grid 32 x 40 = 1280 blocks
    k_gemm<128, 64, HS, HS, true><<<dim3(FFN / 64, MAXT128), 256, 0, stream>>>(
        xbf, w1T, Hb, rowtok, te128, tr128, FFN);
    // GEMM2 -> bf16 partials: 64x64 tiles, split-K=2, grid 8 x 72 x 2 = 1152 blocks
    k_gemm<64, 64, FFN, FFN / 2, false><<<dim3(HS / 64, MAXT64, 2), 256, 0, stream>>>(
        Hb, w2T, outv, rowtok, te64, tr64, HS);
    // combine split-K partials into y and buffer (writes ALL buffer slots)
    k_combine<<<NTOK * HS / 8 / 256, 256, 0, stream>>>(
        outv, ei, ew, hrof, y, buf);
}

// Round 9
// 83.888 us; speedup vs baseline: 1.2060x; 1.0567x over previous
//
#include <hip/hip_runtime.h>
#include <hip/hip_bf16.h>

// Problem constants
#define NTOK 2048
#define TOPK 2
#define HS   512
#define FFN  2048
#define NE   8
#define TASSIGN (NTOK*TOPK)   // 4096
#define PAD  5120             // 4096 + 8*128
#define MAXT128 40
#define MAXT64  72

typedef __attribute__((ext_vector_type(8))) short bf16x8;
typedef __attribute__((ext_vector_type(8))) unsigned short u16x8;
typedef __attribute__((ext_vector_type(4))) float f32x4;

// ws layout (byte offsets); total ~67.15 MB
static const size_t OFF_XBF  = 0;            // [NTOK*HS] bf16
static const size_t OFF_W1T  = 2097152;      // [E][FFN][HS] bf16
static const size_t OFF_W2T  = 18874368;     // [E][HS][FFN] bf16
static const size_t OFF_H    = 35651584;     // [PAD][FFN] bf16
static const size_t OFF_OUTV = 56623104;     // [2][PAD][HS] bf16 (split-K partials)
static const size_t OFF_RT   = 67108864;     // rowtok [PAD] int
static const size_t OFF_HROF = 67129344;     // hrof [TASSIGN] int
static const size_t OFF_TE128= 67145728;
static const size_t OFF_TR128= 67145888;
static const size_t OFF_TE64 = 67146048;
static const size_t OFF_TR64 = 67146336;

__device__ __forceinline__ unsigned short f2bf(float f) {
    union { __hip_bfloat16 h; unsigned short u; } v;
    v.h = __float2bfloat16(f);
    return v.u;
}

__device__ __forceinline__ float bf2f(unsigned short u) {
    union { unsigned int i; float f; } v;
    v.i = ((unsigned int)u) << 16;
    return v.f;
}

__device__ __forceinline__ int swz(int r, int byte_off) {
    return byte_off ^ ((r & 7) << 4);
}

// tanh-approx GELU = x*sigmoid(x*(1.59577 + 0.0713548*x^2)); |err| < 5e-4.
__device__ __forceinline__ float gelu_fast(float x) {
    float z2 = x * fmaf(0.0713548162726f, x * x, 1.5957691216057f);
    float e = __expf(z2);
    return x - __fdividef(x, e + 1.0f);
}

#define GLOAD16(gsrc, ldst) \
    __builtin_amdgcn_global_load_lds((const __attribute__((address_space(1))) void*)(gsrc), \
                                     (__attribute__((address_space(3))) void*)(ldst), 16, 0, 0)

// ---- fused prep: setup (block 0) + x->bf16 (1024) + w1T (8192) + w2T (8192) ----
__device__ __forceinline__ void dev_transpose(const float* __restrict__ in,
                                              unsigned short* __restrict__ out,
                                              int R, int C, int e, int rb, int cb, int tid) {
    __shared__ unsigned short t[32][33];
    int tx = tid & 31, ty = tid >> 5;          // 32 x 8
    const float* ip = in + (size_t)e * R * C;
    unsigned short* op = out + (size_t)e * C * R;
#pragma unroll
    for (int i = 0; i < 4; i++) {
        int r = ty + i * 8;
        t[r][tx] = f2bf(ip[(size_t)(rb + r) * C + cb + tx]);
    }
    __syncthreads();
#pragma unroll
    for (int i = 0; i < 4; i++) {
        int c = ty + i * 8;
        op[(size_t)(cb + c) * R + rb + tx] = t[tx][c];
    }
}

__global__ __launch_bounds__(256) void k_prep(
        const float* __restrict__ x, const float* __restrict__ w1,
        const float* __restrict__ w2, const int* __restrict__ ei,
        unsigned short* __restrict__ xbf, unsigned short* __restrict__ w1T,
        unsigned short* __restrict__ w2T,
        int* __restrict__ rowtok, int* __restrict__ hrof,
        int* __restrict__ te128, int* __restrict__ tr128,
        int* __restrict__ te64, int* __restrict__ tr64) {
    int b = blockIdx.x;
    int tid = threadIdx.x;
    if (b == 0) {
        __shared__ int cnt[NE], offpad[NE], cur[NE];
        for (int i = tid; i < PAD; i += 256) rowtok[i] = 0;
        if (tid < NE) cnt[tid] = 0;
        __syncthreads();
        for (int a = tid; a < TASSIGN; a += 256) atomicAdd(&cnt[ei[a]], 1);
        __syncthreads();
        if (tid == 0) {
            int o = 0, t1 = 0, t2 = 0;
            for (int e = 0; e < NE; e++) {
                offpad[e] = o; cur[e] = 0;
                for (int r = 0; r < cnt[e]; r += 128) { te128[t1] = e; tr128[t1] = o + r; t1++; }
                for (int r = 0; r < cnt[e]; r += 64)  { te64[t2]  = e; tr64[t2]  = o + r; t2++; }
                o += (cnt[e] + 127) / 128 * 128;
            }
            for (; t1 < MAXT128; t1++) te128[t1] = -1;
            for (; t2 < MAXT64;  t2++) te64[t2]  = -1;
        }
        __syncthreads();
        for (int a = tid; a < TASSIGN; a += 256) {
            int e = ei[a];
            int r = atomicAdd(&cur[e], 1);
            int hr = offpad[e] + r;
            rowtok[hr] = a >> 1;       // token = assignment / TOPK
            hrof[a] = hr;
        }
    } else if (b < 1 + 1024) {
        int i = ((b - 1) * 256 + tid) * 4;
        float4 v = *(const float4*)(x + i);
        ushort4 o;
        o.x = f2bf(v.x); o.y = f2bf(v.y); o.z = f2bf(v.z); o.w = f2bf(v.w);
        *(ushort4*)(xbf + i) = o;
    } else if (b < 1 + 1024 + 8192) {
        int blk = b - 1025;
        int e = blk >> 10, rem = blk & 1023;
        dev_transpose(w1, w1T, HS, FFN, e, (rem >> 6) * 32, (rem & 63) * 32, tid);
    } else {
        int blk = b - 9217;
        int e = blk >> 10, rem = blk & 1023;
        dev_transpose(w2, w2T, FFN, HS, e, (rem >> 4) * 32, (rem & 15) * 32, tid);
    }
}

// ---- grouped GEMM: 2-buffer pipeline with COUNTED vmcnt across raw barriers ----
// Per step: [vmcnt(LPS); barrier]  -> buf[s] complete (next step's loads stay in flight)
//           ds_read + MFMA         -> consumes buf[s]
//           [lgkmcnt(0); barrier]  -> all waves done reading buf[s]
//           stage(s+2) into buf[s] -> overwrite now safe
// G1=true:  H = gelu_fast(A_gathered @ B^T-layout), bf16 out (kz unused)
// G1=false: bf16 split-K partials, blockIdx.z selects K-slice
template<int BM, int BN, int KFULL, int KLOC, bool G1>
__global__ __launch_bounds__(256) void k_gemm(
        const unsigned short* __restrict__ A,
        const unsigned short* __restrict__ B,
        unsigned short* __restrict__ outp,
        const int* __restrict__ rowtok,
        const int* __restrict__ te, const int* __restrict__ tr, int N) {
    constexpr int MI = BM / 32, NJ = BN / 32;
    constexpr int PA = BM / 32, PB = BN / 32;       // gload sets of 256 lanes x 16B
    constexpr int ABYTES = BM * 64 * 2, BBYTES = BN * 64 * 2;
    constexpr int NSTEP = KLOC / 64;
    static_assert(NSTEP % 2 == 0 && NSTEP >= 4, "even steps >= 4");

    int mt = blockIdx.y;
    int e = te[mt];
    if (e < 0) return;
    int hr0 = tr[mt];
    int ct = blockIdx.x;
    int kz = blockIdx.z;
    int k0 = kz * KLOC;

    __shared__ int4 ldsv[(2 * (ABYTES + BBYTES)) / 16];
    char* A0 = (char*)ldsv;
    char* A1 = A0 + ABYTES;
    char* B0 = A1 + ABYTES;
    char* B1 = B0 + BBYTES;

    int tid = threadIdx.x;
    int lane = tid & 63, wave = tid >> 6;
    int wm = wave >> 1, wn = wave & 1;

    // per-thread pre-swizzled global sources (chunk c8 of row r fetched from c8^(r&7))
    const char* asrc[PA];
    const char* bsrc[PB];
    int adoff[PA], bdoff[PB];
#pragma unroll
    for (int p = 0; p < PA; p++) {
        int idx = p * 256 + tid;
        int r = idx >> 3, c8 = idx & 7;
        int c8s = c8 ^ (r & 7);
        size_t row = G1 ? (size_t)rowtok[hr0 + r] : (size_t)(hr0 + r);
        asrc[p] = (const char*)(A + row * KFULL + k0) + c8s * 16;
        adoff[p] = (p * 256 + wave * 64) * 16;      // wave-uniform linear LDS dest
    }
#pragma unroll
    for (int p = 0; p < PB; p++) {
        int idx = p * 256 + tid;
        int r = idx >> 3, c8 = idx & 7;
        int c8s = c8 ^ (r & 7);
        bsrc[p] = (const char*)(B + ((size_t)e * N + (size_t)ct * BN + r) * KFULL + k0) + c8s * 16;
        bdoff[p] = (p * 256 + wave * 64) * 16;
    }

    f32x4 acc[MI][NJ] = {};

    auto stage = [&](char* Ad, char* Bd, int s) {
        int kb = s * 128;                            // 64 k-elems * 2B
#pragma unroll
        for (int p = 0; p < PA; p++) GLOAD16(asrc[p] + kb, Ad + adoff[p]);
#pragma unroll
        for (int p = 0; p < PB; p++) GLOAD16(bsrc[p] + kb, Bd + bdoff[p]);
    };
    auto compute = [&](const char* As, const char* Bs) {
#pragma unroll
        for (int kk = 0; kk < 64; kk += 32) {
            bf16x8 af[MI], bfv[NJ];
#pragma unroll
            for (int i = 0; i < MI; i++) {
                int ar = wm * (BM / 2) + i * 16 + (lane & 15);
                af[i] = *(const bf16x8*)(As + swz(ar, ar * 128 + kk * 2 + (lane >> 4) * 16));
            }
#pragma unroll
            for (int j = 0; j < NJ; j++) {
                int bc = wn * (BN / 2) + j * 16 + (lane & 15);
                bfv[j] = *(const bf16x8*)(Bs + swz(bc, bc * 128 + kk * 2 + (lane >> 4) * 16));
            }
#pragma unroll
            for (int i = 0; i < MI; i++)
#pragma unroll
                for (int j = 0; j < NJ; j++)
                    acc[i][j] = __builtin_amdgcn_mfma_f32_16x16x32_bf16(af[i], bfv[j], acc[i][j], 0, 0, 0);
        }
    };
    // counted vmcnt: wait until only the NEWEST stage (LPS loads) remains in flight
    auto waitv_lps = [&]() {
        if constexpr (PA + PB == 6)      { asm volatile("s_waitcnt vmcnt(6)" ::: "memory"); }
        else if constexpr (PA + PB == 4) { asm volatile("s_waitcnt vmcnt(4)" ::: "memory"); }
        else                             { asm volatile("s_waitcnt vmcnt(0)" ::: "memory"); }
    };
    auto waitv0 = [&]() { asm volatile("s_waitcnt vmcnt(0)" ::: "memory"); };
    auto waitlgkm = [&]() { asm volatile("s_waitcnt lgkmcnt(0)" ::: "memory"); };
    auto bar = [&]() {
        __builtin_amdgcn_sched_barrier(0);
        __builtin_amdgcn_s_barrier();
        __builtin_amdgcn_sched_barrier(0);
        asm volatile("" ::: "memory");
    };

    // prologue: two stages in flight
    stage(A0, B0, 0);
    stage(A1, B1, 1);
#pragma unroll 1
    for (int s = 0; s + 2 < NSTEP; s += 2) {
        waitv_lps(); bar();                 // buf0(step s) ready; step s+1 still in flight
        compute(A0, B0);
        waitlgkm(); bar();                  // all waves done reading buf0
        stage(A0, B0, s + 2);
        waitv_lps(); bar();                 // buf1(step s+1) ready
        compute(A1, B1);
        waitlgkm(); bar();
        if (s + 3 < NSTEP) stage(A1, B1, s + 3);
    }
    // tail: steps NSTEP-2 (buf0) and NSTEP-1 (buf1), no more staging
    waitv_lps(); bar();
    compute(A0, B0);
    waitv0(); bar();
    compute(A1, B1);

    if constexpr (G1) {
#pragma unroll
        for (int i = 0; i < MI; i++)
#pragma unroll
            for (int j = 0; j < NJ; j++)
#pragma unroll
                for (int q = 0; q < 4; q++) {
                    int row = hr0 + wm * (BM / 2) + i * 16 + (lane >> 4) * 4 + q;
                    int col = ct * BN + wn * (BN / 2) + j * 16 + (lane & 15);
                    outp[(size_t)row * N + col] = f2bf(gelu_fast(acc[i][j][q]));
                }
    } else {
        unsigned short* O = outp + (size_t)kz * PAD * HS;
#pragma unroll
        for (int i = 0; i < MI; i++)
#pragma unroll
            for (int j = 0; j < NJ; j++)
#pragma unroll
                for (int q = 0; q < 4; q++) {
                    int row = hr0 + wm * (BM / 2) + i * 16 + (lane >> 4) * 4 + q;
                    int col = ct * BN + wn * (BN / 2) + j * 16 + (lane & 15);
                    O[(size_t)row * N + col] = f2bf(acc[i][j][q]);
                }
    }
}

// ---- combine: sum bf16 split-K partials; y[t] = w0*o0 + w1*o1 ;
//      buffer[t][0..7] fully written (zeros incl.) -> no memset anywhere. ----
__global__ __launch_bounds__(256) void k_combine(
        const unsigned short* __restrict__ outv, const int* __restrict__ ei,
        const float* __restrict__ ew, const int* __restrict__ hrof,
        float* __restrict__ y, float* __restrict__ buf) {
    constexpr size_t SPLIT = (size_t)PAD * HS;   // elements between partials
    int g = blockIdx.x * 256 + threadIdx.x;      // over NTOK*HS/8
    int t = g >> 6, c8 = g & 63;                 // HS/8 = 64 chunks/token
    int a0 = 2 * t, a1 = a0 + 1;
    int h0 = hrof[a0], h1 = hrof[a1];
    u16x8 q0a = *(const u16x8*)(outv + (size_t)h0 * HS + c8 * 8);
    u16x8 q0b = *(const u16x8*)(outv + SPLIT + (size_t)h0 * HS + c8 * 8);
    u16x8 q1a = *(const u16x8*)(outv + (size_t)h1 * HS + c8 * 8);
    u16x8 q1b = *(const u16x8*)(outv + SPLIT + (size_t)h1 * HS + c8 * 8);
    float w0 = ew[a0], w1 = ew[a1];
    float o0[8], o1[8], yy[8];
#pragma unroll
    for (int k = 0; k < 8; k++) {
        o0[k] = bf2f(q0a[k]) + bf2f(q0b[k]);
        o1[k] = bf2f(q1a[k]) + bf2f(q1b[k]);
        yy[k] = w0 * o0[k] + w1 * o1[k];
    }
    float* yp = y + (size_t)t * HS + c8 * 8;
    *(float4*)(yp)     = make_float4(yy[0], yy[1], yy[2], yy[3]);
    *(float4*)(yp + 4) = make_float4(yy[4], yy[5], yy[6], yy[7]);
    int e0 = ei[a0], e1 = ei[a1];
    float* bt = buf + (size_t)t * (NE * HS) + c8 * 8;
#pragma unroll
    for (int e = 0; e < NE; e++) {
        float v[8];
#pragma unroll
        for (int k = 0; k < 8; k++)
            v[k] = (e == e0 ? o0[k] : 0.0f) + (e == e1 ? o1[k] : 0.0f);
        float* be = bt + (size_t)e * HS;
        *(float4*)(be)     = make_float4(v[0], v[1], v[2], v[3]);
        *(float4*)(be + 4) = make_float4(v[4], v[5], v[6], v[7]);
    }
}

extern "C" void kernel_launch(void* const* d_in, const int* in_sizes, int n_in,
                              void* d_out, int out_size, void* d_ws, size_t ws_size,
                              hipStream_t stream) {
    const float* x  = (const float*)d_in[0];
    const float* ew = (const float*)d_in[1];
    const int*   ei = (const int*)d_in[2];
    const float* w1 = (const float*)d_in[3];
    const float* w2 = (const float*)d_in[4];

    char* ws = (char*)d_ws;
    unsigned short* xbf  = (unsigned short*)(ws + OFF_XBF);
    unsigned short* w1T  = (unsigned short*)(ws + OFF_W1T);
    unsigned short* w2T  = (unsigned short*)(ws + OFF_W2T);
    unsigned short* Hb   = (unsigned short*)(ws + OFF_H);
    unsigned short* outv = (unsigned short*)(ws + OFF_OUTV);
    int*            rowtok = (int*)(ws + OFF_RT);
    int*            hrof   = (int*)(ws + OFF_HROF);
    int*            te128  = (int*)(ws + OFF_TE128);
    int*            tr128  = (int*)(ws + OFF_TR128);
    int*            te64   = (int*)(ws + OFF_TE64);
    int*            tr64   = (int*)(ws + OFF_TR64);

    float* y   = (float*)d_out;
    float* buf = (float*)d_out + (size_t)NTOK * HS;

    // fused prep: setup + xcvt + both weight transposes, one launch
    k_prep<<<1 + 1024 + 8192 + 8192, 256, 0, stream>>>(
        x, w1, w2, ei, xbf, w1T, w2T, rowtok, hrof, te128, tr128, te64, tr64);
    // GEMM1 + fast gelu -> H (bf16): 128x64 tiles, grid 32 x 40 = 1280 blocks
    k_gemm<128, 64, HS, HS, true><<<dim3(FFN / 64, MAXT128), 256, 0, stream>>>(
        xbf, w1T, Hb, rowtok, te128, tr128, FFN);
    // GEMM2 -> bf16 partials: 64x64 tiles, split-K=2, grid 8 x 72 x 2 = 1152 blocks
    k_gemm<64, 64, FFN, FFN / 2, false><<<dim3(HS / 64, MAXT64, 2), 256, 0, stream>>>(
        Hb, w2T, outv, rowtok, te64, tr64, HS);
    // combine split-K partials into y and buffer (writes ALL buffer slots)
    k_combine<<<NTOK * HS / 8 / 256, 256, 0, stream>>>(
        outv, ei, ew, hrof, y, buf);
}